// Round 1
// baseline (323.846 us; speedup 1.0000x reference)
//
#include <hip/hip_runtime.h>
#include <math.h>

// out = relu( tile(pool2(x1),2) + tile(pool4(x2),4) + tile(pool8(x3),8)
//             + tile(pool16(x4),16) + ff )   all NCHW fp32, B=16, out 16x256x24x24.
//
// Memory-bound: ideal traffic ~302 MB (read inputs once + ff, write out).
// Two-phase: pool each input into ws (8.85 MB, L2/L3 resident), then combine.

namespace {

constexpr int BATCH = 16;
constexpr int OHW   = 24;            // pooled height == width
constexpr int PLANE = OHW * OHW;     // 576

// p points at the top-left of a KxK window; row stride = `stride` floats.
// Window starts are K-aligned in floats, so float2/float4 loads are aligned.
template <int K>
__device__ __forceinline__ float pool_window(const float* __restrict__ p, int stride) {
  float m = -INFINITY;
  if constexpr (K == 2) {
#pragma unroll
    for (int r = 0; r < 2; ++r) {
      float2 v = *reinterpret_cast<const float2*>(p + r * stride);
      m = fmaxf(m, fmaxf(v.x, v.y));
    }
  } else {
#pragma unroll
    for (int r = 0; r < K; ++r) {
#pragma unroll
      for (int c = 0; c < K; c += 4) {
        float4 v = *reinterpret_cast<const float4*>(p + r * stride + c);
        m = fmaxf(m, fmaxf(fmaxf(v.x, v.y), fmaxf(v.z, v.w)));
      }
    }
  }
  return m;
}

// One thread per pooled output element. Input plane is (OHW*K) x (OHW*K).
template <int K, int C>
__global__ __launch_bounds__(256) void pool_kernel(const float* __restrict__ in,
                                                   float* __restrict__ out) {
  constexpr int W     = OHW * K;   // input width == height
  constexpr int total = BATCH * C * PLANE;
  const int idx = blockIdx.x * 256 + threadIdx.x;
  if (idx >= total) return;
  const int ow = idx % OHW;
  const int oh = (idx / OHW) % OHW;
  const int bc = idx / PLANE;
  const float* p = in + (size_t)bc * (W * W) + (size_t)(oh * K) * W + ow * K;
  out[idx] = pool_window<K>(p, W);
}

// One float4 (4 consecutive hw positions) per thread.
__global__ __launch_bounds__(256) void combine_kernel(const float* __restrict__ p1,
                                                      const float* __restrict__ p2,
                                                      const float* __restrict__ p3,
                                                      const float* __restrict__ p4,
                                                      const float* __restrict__ ff,
                                                      float* __restrict__ out) {
  constexpr int total4 = BATCH * 256 * PLANE / 4;
  const int idx = blockIdx.x * 256 + threadIdx.x;
  if (idx >= total4) return;
  const int hw4 = idx % (PLANE / 4);
  const int c   = (idx / (PLANE / 4)) % 256;
  const int b   = idx / ((PLANE / 4) * 256);
  const int hw  = hw4 * 4;

  const float4 a1 = *reinterpret_cast<const float4*>(p1 + (size_t)(b * 128 + (c & 127)) * PLANE + hw);
  const float4 a2 = *reinterpret_cast<const float4*>(p2 + (size_t)(b * 64  + (c & 63 )) * PLANE + hw);
  const float4 a3 = *reinterpret_cast<const float4*>(p3 + (size_t)(b * 32  + (c & 31 )) * PLANE + hw);
  const float4 a4 = *reinterpret_cast<const float4*>(p4 + (size_t)(b * 16  + (c & 15 )) * PLANE + hw);
  const float4 f  = *reinterpret_cast<const float4*>(ff + (size_t)idx * 4);

  float4 r;
  r.x = fmaxf((((a1.x + a2.x) + a3.x) + a4.x) + f.x, 0.0f);
  r.y = fmaxf((((a1.y + a2.y) + a3.y) + a4.y) + f.y, 0.0f);
  r.z = fmaxf((((a1.z + a2.z) + a3.z) + a4.z) + f.z, 0.0f);
  r.w = fmaxf((((a1.w + a2.w) + a3.w) + a4.w) + f.w, 0.0f);
  *reinterpret_cast<float4*>(out + (size_t)idx * 4) = r;
}

// Fallback (tiny ws): fully fused, recomputes windows per output channel.
__global__ __launch_bounds__(256) void fused_naive(const float* __restrict__ x1,
                                                   const float* __restrict__ x2,
                                                   const float* __restrict__ x3,
                                                   const float* __restrict__ x4,
                                                   const float* __restrict__ ff,
                                                   float* __restrict__ out) {
  constexpr int total = BATCH * 256 * PLANE;
  const int idx = blockIdx.x * 256 + threadIdx.x;
  if (idx >= total) return;
  const int hw = idx % PLANE;
  const int w  = hw % OHW;
  const int h  = hw / OHW;
  const int c  = (idx / PLANE) % 256;
  const int b  = idx / (PLANE * 256);

  float s = pool_window<2>(x1 + (size_t)(b * 128 + (c & 127)) * (48 * 48)   + (size_t)(h * 2)  * 48  + w * 2,  48);
  s = s + pool_window<4>( x2 + (size_t)(b * 64  + (c & 63 )) * (96 * 96)   + (size_t)(h * 4)  * 96  + w * 4,  96);
  s = s + pool_window<8>( x3 + (size_t)(b * 32  + (c & 31 )) * (192 * 192) + (size_t)(h * 8)  * 192 + w * 8,  192);
  s = s + pool_window<16>(x4 + (size_t)(b * 16  + (c & 15 )) * (384 * 384) + (size_t)(h * 16) * 384 + w * 16, 384);
  s = s + ff[idx];
  out[idx] = fmaxf(s, 0.0f);
}

}  // namespace

extern "C" void kernel_launch(void* const* d_in, const int* in_sizes, int n_in,
                              void* d_out, int out_size, void* d_ws, size_t ws_size,
                              hipStream_t stream) {
  const float* x1 = (const float*)d_in[0];  // [16,128,48,48]
  const float* x2 = (const float*)d_in[1];  // [16,64,96,96]
  const float* x3 = (const float*)d_in[2];  // [16,32,192,192]
  const float* x4 = (const float*)d_in[3];  // [16,16,384,384]
  const float* ff = (const float*)d_in[4];  // [16,256,24,24]
  float* out = (float*)d_out;               // [16,256,24,24]

  constexpr size_t n1 = (size_t)BATCH * 128 * PLANE;  // 1,179,648
  constexpr size_t n2 = (size_t)BATCH * 64  * PLANE;  //   589,824
  constexpr size_t n3 = (size_t)BATCH * 32  * PLANE;  //   294,912
  constexpr size_t n4 = (size_t)BATCH * 16  * PLANE;  //   147,456
  constexpr size_t need = (n1 + n2 + n3 + n4) * sizeof(float);  // 8.85 MB

  if (ws_size >= need) {
    float* p1 = (float*)d_ws;
    float* p2 = p1 + n1;
    float* p3 = p2 + n2;
    float* p4 = p3 + n3;
    pool_kernel<2, 128><<<n1 / 256, 256, 0, stream>>>(x1, p1);
    pool_kernel<4, 64 ><<<n2 / 256, 256, 0, stream>>>(x2, p2);
    pool_kernel<8, 32 ><<<n3 / 256, 256, 0, stream>>>(x3, p3);
    pool_kernel<16, 16><<<n4 / 256, 256, 0, stream>>>(x4, p4);
    constexpr int total4 = BATCH * 256 * PLANE / 4;   // 589,824
    combine_kernel<<<total4 / 256, 256, 0, stream>>>(p1, p2, p3, p4, ff, out);
  } else {
    constexpr int total = BATCH * 256 * PLANE;
    fused_naive<<<(total + 255) / 256, 256, 0, stream>>>(x1, x2, x3, x4, ff, out);
  }
}

// Round 3
// 314.252 us; speedup vs baseline: 1.0305x; 1.0305x over previous
//
#include <hip/hip_runtime.h>
#include <math.h>

// out = relu( tile(pool2(x1),2) + tile(pool4(x2),4) + tile(pool8(x3),8)
//             + tile(pool16(x4),16) + ff )   all NCHW fp32, B=16, out 16x256x24x24.
//
// Round-3: SINGLE kernel, zero workspace (round-2's pool->combine two-dispatch
// pipeline through d_ws diverged under graph replay; removing the cross-dispatch
// dependency removes the hazard class entirely).
//
// Block = (b, oh, column-half): 16*24*2 = 768 blocks = exactly 3 blocks/CU.
// Each block pools ALL input channels for its 12 output columns into LDS
// (each input element is read exactly once device-wide; ~283 MB total),
// then combines + relu + writes 256 channels x 12 cols.
// Phases A-D each have exactly 768 lane-tasks = 3 iters x 256 threads.

namespace {

constexpr int OHW = 24;

__device__ __forceinline__ float fmax4(const float4 v) {
  return fmaxf(fmaxf(v.x, v.y), fmaxf(v.z, v.w));
}

__global__ __launch_bounds__(256, 3) void fused_block(const float* __restrict__ x1,
                                                      const float* __restrict__ x2,
                                                      const float* __restrict__ x3,
                                                      const float* __restrict__ x4,
                                                      const float* __restrict__ ff,
                                                      float* __restrict__ out) {
  __shared__ __attribute__((aligned(16))) float s1[128 * 12];
  __shared__ __attribute__((aligned(16))) float s2[64 * 12];
  __shared__ __attribute__((aligned(16))) float s3[32 * 12];
  __shared__ __attribute__((aligned(16))) float s4[16 * 12];

  const int blk  = blockIdx.x;     // 0..767
  const int b    = blk / 48;
  const int rem  = blk % 48;
  const int oh   = rem >> 1;       // 0..23
  const int half = rem & 1;        // 0..1  (output cols half*12 .. half*12+11)
  const int tid  = threadIdx.x;

  // ---- Phase A: x1 [16,128,48,48], K=2. task = ch(128) x pid(6); pid = float4
  //      covering 2 adjacent windows (4 input cols). 2 row loads. ----
  {
    const float* base = x1 + (size_t)b * 128 * 2304 + oh * 2 * 48 + half * 24;
#pragma unroll
    for (int it = 0; it < 3; ++it) {
      const int t  = it * 256 + tid;
      const int ch = t / 6, pid = t % 6;
      const float* p = base + (size_t)ch * 2304 + pid * 4;
      const float4 a = *reinterpret_cast<const float4*>(p);
      const float4 c = *reinterpret_cast<const float4*>(p + 48);
      s1[ch * 12 + pid * 2]     = fmaxf(fmaxf(a.x, a.y), fmaxf(c.x, c.y));
      s1[ch * 12 + pid * 2 + 1] = fmaxf(fmaxf(a.z, a.w), fmaxf(c.z, c.w));
    }
  }

  // ---- Phase B: x2 [16,64,96,96], K=4. task = ch(64) x ow(12); 4 row loads. ----
  {
    const float* base = x2 + (size_t)b * 64 * 9216 + oh * 4 * 96 + half * 48;
#pragma unroll
    for (int it = 0; it < 3; ++it) {
      const int t  = it * 256 + tid;
      const int ch = t / 12, ow = t % 12;
      const float* p = base + (size_t)ch * 9216 + ow * 4;
      float m = -INFINITY;
#pragma unroll
      for (int r = 0; r < 4; ++r)
        m = fmaxf(m, fmax4(*reinterpret_cast<const float4*>(p + r * 96)));
      s2[ch * 12 + ow] = m;
    }
  }

  // ---- Phase C: x3 [16,32,192,192], K=8. task = ch(32) x ow(12) x hf(2);
  //      2 lanes/window (column halves), 8 row loads, shfl reduce. ----
  {
    const float* base = x3 + (size_t)b * 32 * 36864 + oh * 8 * 192 + half * 96;
#pragma unroll
    for (int it = 0; it < 3; ++it) {
      const int t  = it * 256 + tid;
      const int ch = t / 24, ow = (t % 24) >> 1, hf = t & 1;
      const float* p = base + (size_t)ch * 36864 + ow * 8 + hf * 4;
      float m = -INFINITY;
#pragma unroll
      for (int r = 0; r < 8; ++r)
        m = fmaxf(m, fmax4(*reinterpret_cast<const float4*>(p + r * 192)));
      m = fmaxf(m, __shfl_xor(m, 1));
      if (hf == 0) s3[ch * 12 + ow] = m;
    }
  }

  // ---- Phase D: x4 [16,16,384,384], K=16. task = ch(16) x ow(12) x q(4);
  //      4 lanes/window (column quarters), 16 row loads, shfl reduce. ----
  {
    const float* base = x4 + (size_t)b * 16 * 147456 + oh * 16 * 384 + half * 192;
#pragma unroll
    for (int it = 0; it < 3; ++it) {
      const int t  = it * 256 + tid;
      const int ch = t / 48, ow = (t % 48) >> 2, q = t & 3;
      const float* p = base + (size_t)ch * 147456 + ow * 16 + q * 4;
      float m = -INFINITY;
#pragma unroll
      for (int r = 0; r < 16; ++r)
        m = fmaxf(m, fmax4(*reinterpret_cast<const float4*>(p + r * 384)));
      m = fmaxf(m, __shfl_xor(m, 1));
      m = fmaxf(m, __shfl_xor(m, 2));
      if (q == 0) s4[ch * 12 + ow] = m;
    }
  }

  __syncthreads();

  // ---- Phase E: combine. task = c(256) x colquad(3); float4 over 4 cols. ----
  {
    const size_t obase = (size_t)b * 256 * 576 + oh * OHW + half * 12;
#pragma unroll
    for (int it = 0; it < 3; ++it) {
      const int t = it * 256 + tid;
      const int c = t / 3, q = (t % 3) * 4;
      const float4 a1 = *reinterpret_cast<const float4*>(&s1[(c & 127) * 12 + q]);
      const float4 a2 = *reinterpret_cast<const float4*>(&s2[(c & 63)  * 12 + q]);
      const float4 a3 = *reinterpret_cast<const float4*>(&s3[(c & 31)  * 12 + q]);
      const float4 a4 = *reinterpret_cast<const float4*>(&s4[(c & 15)  * 12 + q]);
      const size_t o  = obase + (size_t)c * 576 + q;
      const float4 f  = *reinterpret_cast<const float4*>(ff + o);
      float4 r;
      r.x = fmaxf((((a1.x + a2.x) + a3.x) + a4.x) + f.x, 0.0f);
      r.y = fmaxf((((a1.y + a2.y) + a3.y) + a4.y) + f.y, 0.0f);
      r.z = fmaxf((((a1.z + a2.z) + a3.z) + a4.z) + f.z, 0.0f);
      r.w = fmaxf((((a1.w + a2.w) + a3.w) + a4.w) + f.w, 0.0f);
      *reinterpret_cast<float4*>(out + o) = r;
    }
  }
}

}  // namespace

extern "C" void kernel_launch(void* const* d_in, const int* in_sizes, int n_in,
                              void* d_out, int out_size, void* d_ws, size_t ws_size,
                              hipStream_t stream) {
  const float* x1 = (const float*)d_in[0];  // [16,128,48,48]
  const float* x2 = (const float*)d_in[1];  // [16,64,96,96]
  const float* x3 = (const float*)d_in[2];  // [16,32,192,192]
  const float* x4 = (const float*)d_in[3];  // [16,16,384,384]
  const float* ff = (const float*)d_in[4];  // [16,256,24,24]
  float* out = (float*)d_out;               // [16,256,24,24]
  (void)d_ws; (void)ws_size; (void)in_sizes; (void)n_in; (void)out_size;

  fused_block<<<768, 256, 0, stream>>>(x1, x2, x3, x4, ff, out);
}